// Round 6
// baseline (343.907 us; speedup 1.0000x reference)
//
#include <hip/hip_runtime.h>

// GCN 2-layer forward. f32 wire; bf16 MFMA GEMMs (f32 acc); bf16 gather tables;
// padded-ELL adjacency; octet-interleaved fill+gemm1 (XCD-affine atomics).
// This round: revert R5's sort (regressed); PAD deg counters to one per 64B
// cache line (stride 16 ints) to eliminate same-line atomic RMW serialization.

#define DIN 128
#define DHID 128
#define DOUT 64
#define ELLW 64     // max in-degree (Poisson(16): P(>=64) ~ 1e-22)
#define GPART 8
#define BPG 512
#define DEGS 16     // deg counter stride (ints): one counter per 64B line

typedef __attribute__((ext_vector_type(4))) float f32x4;
typedef __attribute__((ext_vector_type(8))) short bf16x8;

__device__ __forceinline__ float bf2f(unsigned int u16) {
    return __uint_as_float(u16 << 16);
}
__device__ __forceinline__ unsigned short f2bf(float f) {
    unsigned int u = __float_as_uint(f);
    u += 0x7fffu + ((u >> 16) & 1u);   // RNE
    return (unsigned short)(u >> 16);
}
__device__ __forceinline__ unsigned int pack2(float a, float b) {
    return (unsigned int)f2bf(a) | ((unsigned int)f2bf(b) << 16);
}

// ---------------- pack W1/W2 into MFMA B-fragment order, bf16; zero deg ----------------
__global__ __launch_bounds__(256) void k_packW(const float* __restrict__ W1,
                                               const float* __restrict__ W2,
                                               unsigned short* __restrict__ w1p,
                                               unsigned short* __restrict__ w2p,
                                               int* __restrict__ degp, int N) {
    int id = blockIdx.x * 256 + threadIdx.x;
    if (id < 2048) {                     // W1: 8 n-tiles x 4 k-steps x 64 lanes
        int lane = id & 63, s = (id >> 6) & 3, t = id >> 8;
        int n = t * 16 + (lane & 15);
        int k0 = s * 32 + (lane >> 4) * 8;
#pragma unroll
        for (int j = 0; j < 8; ++j)
            w1p[(size_t)id * 8 + j] = f2bf(W1[(k0 + j) * DHID + n]);
    } else if (id < 3072) {              // W2: 4 n-tiles x 4 k-steps x 64 lanes
        int id2 = id - 2048;
        int lane = id2 & 63, s = (id2 >> 6) & 3, t = id2 >> 8;
        int n = t * 16 + (lane & 15);
        int k0 = s * 32 + (lane >> 4) * 8;
#pragma unroll
        for (int j = 0; j < 8; ++j)
            w2p[(size_t)id2 * 8 + j] = f2bf(W2[(k0 + j) * DOUT + n]);
    }
    for (int i = id; i < N; i += 12 * 256) degp[(size_t)i * DEGS] = 0;
}

// ---------------- fused: ELL fill + GEMM1, octet-interleaved roles ----------------
__device__ __forceinline__ void fill_edge(int c, int r, int lo, int hi,
                                          int* __restrict__ degp, int* __restrict__ ell) {
    if (c >= lo && c < hi) {
        int k = atomicAdd(&degp[(size_t)c * DEGS], 1);
        if (k < ELLW) ell[(size_t)c * ELLW + k] = r;
    }
}

__global__ __launch_bounds__(256) void k_fill_gemm1(
        const int* __restrict__ rows, const int* __restrict__ cols,
        int* __restrict__ degp, int* __restrict__ ell,
        int E, int perBlock, int R, int GOCT, int GB,
        const float* __restrict__ x, const unsigned short* __restrict__ w1p,
        unsigned short* __restrict__ h1b, int N) {
    int bid = (int)blockIdx.x;
    int o = bid >> 3;
    int lane7 = bid & 7;
    int m = o / 3;
    int p = o - 3 * m;
    if (p == 2 && m < GOCT) {
        // ----- GEMM1 (MFMA): h1b[N,128] bf16 = bf16(x) @ w1p -----
        int gemmIdx = m * 8 + lane7;
        if (gemmIdx >= GB) return;
        int wave = threadIdx.x >> 6, lane = threadIdx.x & 63;
        int quad = lane >> 4, qr = lane & 15;
        int rowBase = gemmIdx * 64 + wave * 16;
        int arow = rowBase + qr;
        bool rowOK = arow < N;
        f32x4 acc[8] = {};
#pragma unroll
        for (int s = 0; s < 4; ++s) {
            bf16x8 a = {};
            if (rowOK) {
                const float* ap = x + (size_t)arow * DIN + s * 32 + quad * 8;
                float4 lo = *(const float4*)ap;
                float4 hi = *(const float4*)(ap + 4);
                a[0] = (short)f2bf(lo.x); a[1] = (short)f2bf(lo.y);
                a[2] = (short)f2bf(lo.z); a[3] = (short)f2bf(lo.w);
                a[4] = (short)f2bf(hi.x); a[5] = (short)f2bf(hi.y);
                a[6] = (short)f2bf(hi.z); a[7] = (short)f2bf(hi.w);
            }
#pragma unroll
            for (int t = 0; t < 8; ++t) {
                bf16x8 b = *(const bf16x8*)(w1p + ((size_t)(t * 4 + s) * 64 + lane) * 8);
                acc[t] = __builtin_amdgcn_mfma_f32_16x16x32_bf16(a, b, acc[t], 0, 0, 0);
            }
        }
#pragma unroll
        for (int t = 0; t < 8; ++t)
#pragma unroll
            for (int i = 0; i < 4; ++i) {
                int r = rowBase + quad * 4 + i;
                if (r < N) h1b[(size_t)r * DHID + t * 16 + qr] = f2bf(acc[t][i]);
            }
        return;
    }
    // ----- ELL fill, dst-range partitioned (group = bid&7 = XCD-affine), int4 scan -----
    int gemBefore = (m < GOCT) ? m : GOCT;
    int chunk = o - gemBefore;                  // 0 .. BPG-1
    int g = lane7;
    int lo = g * R, hi = lo + R;
    int eBeg = chunk * perBlock;
    int eEnd = eBeg + perBlock; if (eEnd > E) eEnd = E;
    for (int e = eBeg + 4 * threadIdx.x; e < eEnd; e += 4 * 256) {
        if (e + 3 < eEnd) {
            int4 c4 = *(const int4*)(cols + e);
            int4 r4 = *(const int4*)(rows + e);
            fill_edge(c4.x, r4.x, lo, hi, degp, ell);
            fill_edge(c4.y, r4.y, lo, hi, degp, ell);
            fill_edge(c4.z, r4.z, lo, hi, degp, ell);
            fill_edge(c4.w, r4.w, lo, hi, degp, ell);
        } else {
            for (int j = e; j < eEnd; ++j) fill_edge(cols[j], rows[j], lo, hi, degp, ell);
        }
    }
}

// ---------------- gather layer 1 (wide): 2 rows/round, 8B/lane ----------------
// one wave per dst node; half-wave h (lane>>5) handles rows e+h; lane&31 = uint2
// column (features 4c..4c+3). Cross-half combine via shfl_xor(32) at the end.
__global__ __launch_bounds__(256) void k_gather1(const int* __restrict__ degp,
                                                 const int* __restrict__ ell,
                                                 const uint2* __restrict__ h1v,
                                                 const float* __restrict__ b1,
                                                 uint2* __restrict__ hactv, int N) {
    int w = (blockIdx.x * 256 + threadIdx.x) >> 6;
    int lane = threadIdx.x & 63;
    if (w >= N) return;
    int d = degp[(size_t)w * DEGS]; if (d > ELLW) d = ELLW;
    int iv0 = ell[(size_t)w * ELLW + lane];                     // 256B coalesced
    int iv = (lane < d) ? iv0 : 0;                              // safe index
    float dv = (lane < d) ? rsqrtf((float)(degp[(size_t)iv * DEGS] + 1)) : 0.f;
    int half = lane >> 5, col = lane & 31;
    float a0 = 0.f, a1 = 0.f, a2 = 0.f, a3 = 0.f;
    int e = 0;
    for (; e + 16 <= d; e += 16) {                              // 16 rows, 8 loads
        int s[8]; float wg[8]; uint2 v[8];
#pragma unroll
        for (int j = 0; j < 8; ++j) {
            int idx = e + 2 * j + half;
            s[j] = __shfl(iv, idx); wg[j] = __shfl(dv, idx);
        }
#pragma unroll
        for (int j = 0; j < 8; ++j) v[j] = h1v[(size_t)s[j] * 32 + col];
#pragma unroll
        for (int j = 0; j < 8; ++j) {
            a0 = fmaf(wg[j], bf2f(v[j].x & 0xffffu), a0);
            a1 = fmaf(wg[j], bf2f(v[j].x >> 16), a1);
            a2 = fmaf(wg[j], bf2f(v[j].y & 0xffffu), a2);
            a3 = fmaf(wg[j], bf2f(v[j].y >> 16), a3);
        }
    }
    for (; e + 8 <= d; e += 8) {                                // 8 rows, 4 loads
        int s[4]; float wg[4]; uint2 v[4];
#pragma unroll
        for (int j = 0; j < 4; ++j) {
            int idx = e + 2 * j + half;
            s[j] = __shfl(iv, idx); wg[j] = __shfl(dv, idx);
        }
#pragma unroll
        for (int j = 0; j < 4; ++j) v[j] = h1v[(size_t)s[j] * 32 + col];
#pragma unroll
        for (int j = 0; j < 4; ++j) {
            a0 = fmaf(wg[j], bf2f(v[j].x & 0xffffu), a0);
            a1 = fmaf(wg[j], bf2f(v[j].x >> 16), a1);
            a2 = fmaf(wg[j], bf2f(v[j].y & 0xffffu), a2);
            a3 = fmaf(wg[j], bf2f(v[j].y >> 16), a3);
        }
    }
    for (; e < d; e += 2) {                                     // tail pair
        int idx = e + half;                                     // beyond-d lanes: wg=0
        int s0 = __shfl(iv, idx); float w0 = __shfl(dv, idx);
        uint2 v0 = h1v[(size_t)s0 * 32 + col];
        a0 = fmaf(w0, bf2f(v0.x & 0xffffu), a0);
        a1 = fmaf(w0, bf2f(v0.x >> 16), a1);
        a2 = fmaf(w0, bf2f(v0.y & 0xffffu), a2);
        a3 = fmaf(w0, bf2f(v0.y >> 16), a3);
    }
    a0 += __shfl_xor(a0, 32); a1 += __shfl_xor(a1, 32);
    a2 += __shfl_xor(a2, 32); a3 += __shfl_xor(a3, 32);
    float di = rsqrtf((float)(d + 1)), self = di * di;
    uint2 hv = h1v[(size_t)w * 32 + col];
    float4 bv = *(const float4*)(b1 + 4 * col);
    float r0 = fmaf(di, a0, fmaf(self, bf2f(hv.x & 0xffffu), bv.x));
    float r1 = fmaf(di, a1, fmaf(self, bf2f(hv.x >> 16), bv.y));
    float r2 = fmaf(di, a2, fmaf(self, bf2f(hv.y & 0xffffu), bv.z));
    float r3 = fmaf(di, a3, fmaf(self, bf2f(hv.y >> 16), bv.w));
    if (lane < 32) {
        uint2 ov;
        ov.x = pack2(fmaxf(r0, 0.f), fmaxf(r1, 0.f));
        ov.y = pack2(fmaxf(r2, 0.f), fmaxf(r3, 0.f));
        hactv[(size_t)w * 32 + col] = ov;
    }
}

// ---------------- GEMM2 (MFMA): h2b[N,64] bf16 = hact(bf16) @ w2p ----------------
__global__ __launch_bounds__(256) void k_gemm2(const unsigned short* __restrict__ hactb,
                                               const unsigned short* __restrict__ w2p,
                                               unsigned short* __restrict__ h2b, int N) {
    int wave = threadIdx.x >> 6, lane = threadIdx.x & 63;
    int quad = lane >> 4, qr = lane & 15;
    int rowBase = blockIdx.x * 64 + wave * 16;
    int arow = rowBase + qr;
    bool rowOK = arow < N;
    f32x4 acc[4] = {};
#pragma unroll
    for (int s = 0; s < 4; ++s) {
        bf16x8 a = {};
        if (rowOK) a = *(const bf16x8*)(hactb + (size_t)arow * DHID + s * 32 + quad * 8);
#pragma unroll
        for (int t = 0; t < 4; ++t) {
            bf16x8 b = *(const bf16x8*)(w2p + ((size_t)(t * 4 + s) * 64 + lane) * 8);
            acc[t] = __builtin_amdgcn_mfma_f32_16x16x32_bf16(a, b, acc[t], 0, 0, 0);
        }
    }
#pragma unroll
    for (int t = 0; t < 4; ++t)
#pragma unroll
        for (int i = 0; i < 4; ++i) {
            int r = rowBase + quad * 4 + i;
            if (r < N) h2b[(size_t)r * DOUT + t * 16 + qr] = f2bf(acc[t][i]);
        }
}

// ---------------- gather layer 2 (wide): 2 rows/round, 4B/lane; writes f32 out ----------------
__global__ __launch_bounds__(256) void k_gather2(const int* __restrict__ degp,
                                                 const int* __restrict__ ell,
                                                 const unsigned int* __restrict__ h2v,
                                                 const float* __restrict__ b2,
                                                 float* __restrict__ out, int N) {
    int w = (blockIdx.x * 256 + threadIdx.x) >> 6;
    int lane = threadIdx.x & 63;
    if (w >= N) return;
    int d = degp[(size_t)w * DEGS]; if (d > ELLW) d = ELLW;
    int iv0 = ell[(size_t)w * ELLW + lane];
    int iv = (lane < d) ? iv0 : 0;
    float dv = (lane < d) ? rsqrtf((float)(degp[(size_t)iv * DEGS] + 1)) : 0.f;
    int half = lane >> 5, col = lane & 31;
    float a0 = 0.f, a1 = 0.f;
    int e = 0;
    for (; e + 16 <= d; e += 16) {
        int s[8]; float wg[8]; unsigned int v[8];
#pragma unroll
        for (int j = 0; j < 8; ++j) {
            int idx = e + 2 * j + half;
            s[j] = __shfl(iv, idx); wg[j] = __shfl(dv, idx);
        }
#pragma unroll
        for (int j = 0; j < 8; ++j) v[j] = h2v[(size_t)s[j] * 32 + col];
#pragma unroll
        for (int j = 0; j < 8; ++j) {
            a0 = fmaf(wg[j], bf2f(v[j] & 0xffffu), a0);
            a1 = fmaf(wg[j], bf2f(v[j] >> 16), a1);
        }
    }
    for (; e + 8 <= d; e += 8) {
        int s[4]; float wg[4]; unsigned int v[4];
#pragma unroll
        for (int j = 0; j < 4; ++j) {
            int idx = e + 2 * j + half;
            s[j] = __shfl(iv, idx); wg[j] = __shfl(dv, idx);
        }
#pragma unroll
        for (int j = 0; j < 4; ++j) v[j] = h2v[(size_t)s[j] * 32 + col];
#pragma unroll
        for (int j = 0; j < 4; ++j) {
            a0 = fmaf(wg[j], bf2f(v[j] & 0xffffu), a0);
            a1 = fmaf(wg[j], bf2f(v[j] >> 16), a1);
        }
    }
    for (; e < d; e += 2) {
        int idx = e + half;
        int s0 = __shfl(iv, idx); float w0 = __shfl(dv, idx);
        unsigned int v0 = h2v[(size_t)s0 * 32 + col];
        a0 = fmaf(w0, bf2f(v0 & 0xffffu), a0);
        a1 = fmaf(w0, bf2f(v0 >> 16), a1);
    }
    a0 += __shfl_xor(a0, 32); a1 += __shfl_xor(a1, 32);
    float di = rsqrtf((float)(d + 1)), self = di * di;
    unsigned int hv = h2v[(size_t)w * 32 + col];
    float2 bv = *(const float2*)(b2 + 2 * col);
    float r0 = fmaf(di, a0, fmaf(self, bf2f(hv & 0xffffu), bv.x));
    float r1 = fmaf(di, a1, fmaf(self, bf2f(hv >> 16), bv.y));
    if (lane < 32) {
        float2 ov; ov.x = r0; ov.y = r1;
        *(float2*)(out + (size_t)w * DOUT + 2 * col) = ov;
    }
}

extern "C" void kernel_launch(void* const* d_in, const int* in_sizes, int n_in,
                              void* d_out, int out_size, void* d_ws, size_t ws_size,
                              hipStream_t stream) {
    const float* x  = (const float*)d_in[0];
    const int*   ei = (const int*)d_in[1];
    const float* W1 = (const float*)d_in[2];
    const float* b1 = (const float*)d_in[3];
    const float* W2 = (const float*)d_in[4];
    const float* b2 = (const float*)d_in[5];

    const int N = in_sizes[0] / DIN;     // 100000
    const int E = in_sizes[1] / 2;       // 1600000
    const int* rows = ei;                // sources
    const int* cols = ei + E;            // destinations

    // workspace (~83.4 MB)
    char* p = (char*)d_ws;
    int*   ell  = (int*)p;                    p += (size_t)N * ELLW * 4;   // 25.6 MB
    unsigned short* h1b = (unsigned short*)p;   p += (size_t)N * DHID * 2; // 25.6 MB
    unsigned short* hactb = (unsigned short*)p; p += (size_t)N * DHID * 2; // 25.6 MB
    unsigned short* w1p = (unsigned short*)p;   p += (size_t)2048 * 8 * 2; // 32 KB
    unsigned short* w2p = (unsigned short*)p;   p += (size_t)1024 * 8 * 2; // 16 KB
    int*   degp = (int*)p;                    p += (size_t)N * DEGS * 4;   // 6.4 MB
    unsigned short* h2b = h1b;   // alias: h1 dead after k_gather1

    const int R = (N + GPART - 1) / GPART;
    int perBlock = (E + BPG - 1) / BPG;
    perBlock = (perBlock + 3) & ~3;                  // int4-aligned chunks
    const int GB = (N + 63) / 64;                    // 1563 gemm tiles
    const int GOCT = (GB + 7) / 8;                   // 196 gemm octets
    const int OCT = BPG + GOCT;                      // 708 octets total

    k_packW<<<12, 256, 0, stream>>>(W1, W2, w1p, w2p, degp, N);

    // fill + gemm1, octet-interleaved (concurrent on every CU)
    k_fill_gemm1<<<8 * OCT, 256, 0, stream>>>(rows, cols, degp, ell, E, perBlock, R,
                                              GOCT, GB, x, w1p, h1b, N);

    // layer 1 aggregate (wide)
    k_gather1<<<(N + 3) / 4, 256, 0, stream>>>(degp, ell, (const uint2*)h1b,
                                               b1, (uint2*)hactb, N);

    // layer 2
    k_gemm2<<<(N + 63) / 64, 256, 0, stream>>>(hactb, w2p, h2b, N);
    k_gather2<<<(N + 3) / 4, 256, 0, stream>>>(degp, ell, (const unsigned int*)h2b,
                                               b2, (float*)d_out, N);
}

// Round 7
// 322.586 us; speedup vs baseline: 1.0661x; 1.0661x over previous
//
#include <hip/hip_runtime.h>

// GCN 2-layer forward. f32 wire; bf16 MFMA GEMMs (f32 acc); bf16 gather tables;
// padded-ELL adjacency; octet-interleaved fill+gemm1 (XCD-affine atomics).
// This round: revert R6 deg padding (compact deg is L2-resident; padding pushed
// gather-side deg reads to L3, +40us). FUSE gemm2 into gather1: each block
// gathers 64 nodes' hact rows into LDS ([64][136] bf16, pad kills 16-way bank
// conflict), one barrier, then MFMA 64x128 @ 128x64 -> h2 direct. Eliminates
// the gemm2 dispatch and the 25.6MB hact global round-trip.

#define DIN 128
#define DHID 128
#define DOUT 64
#define ELLW 64     // max in-degree (Poisson(16): P(>=64) ~ 1e-22)
#define GPART 8
#define BPG 512

typedef __attribute__((ext_vector_type(4))) float f32x4;
typedef __attribute__((ext_vector_type(8))) short bf16x8;

__device__ __forceinline__ float bf2f(unsigned int u16) {
    return __uint_as_float(u16 << 16);
}
__device__ __forceinline__ unsigned short f2bf(float f) {
    unsigned int u = __float_as_uint(f);
    u += 0x7fffu + ((u >> 16) & 1u);   // RNE
    return (unsigned short)(u >> 16);
}
__device__ __forceinline__ unsigned int pack2(float a, float b) {
    return (unsigned int)f2bf(a) | ((unsigned int)f2bf(b) << 16);
}

// ---------------- pack W1/W2 into MFMA B-fragment order, bf16; zero deg ----------------
__global__ __launch_bounds__(256) void k_packW(const float* __restrict__ W1,
                                               const float* __restrict__ W2,
                                               unsigned short* __restrict__ w1p,
                                               unsigned short* __restrict__ w2p,
                                               int* __restrict__ deg, int N) {
    int id = blockIdx.x * 256 + threadIdx.x;
    if (id < 2048) {                     // W1: 8 n-tiles x 4 k-steps x 64 lanes
        int lane = id & 63, s = (id >> 6) & 3, t = id >> 8;
        int n = t * 16 + (lane & 15);
        int k0 = s * 32 + (lane >> 4) * 8;
#pragma unroll
        for (int j = 0; j < 8; ++j)
            w1p[(size_t)id * 8 + j] = f2bf(W1[(k0 + j) * DHID + n]);
    } else if (id < 3072) {              // W2: 4 n-tiles x 4 k-steps x 64 lanes
        int id2 = id - 2048;
        int lane = id2 & 63, s = (id2 >> 6) & 3, t = id2 >> 8;
        int n = t * 16 + (lane & 15);
        int k0 = s * 32 + (lane >> 4) * 8;
#pragma unroll
        for (int j = 0; j < 8; ++j)
            w2p[(size_t)id2 * 8 + j] = f2bf(W2[(k0 + j) * DOUT + n]);
    }
    for (int i = id; i < N; i += 12 * 256) deg[i] = 0;
}

// ---------------- fused: ELL fill + GEMM1, octet-interleaved roles ----------------
__device__ __forceinline__ void fill_edge(int c, int r, int lo, int hi,
                                          int* __restrict__ deg, int* __restrict__ ell) {
    if (c >= lo && c < hi) {
        int k = atomicAdd(&deg[c], 1);
        if (k < ELLW) ell[(size_t)c * ELLW + k] = r;
    }
}

__global__ __launch_bounds__(256) void k_fill_gemm1(
        const int* __restrict__ rows, const int* __restrict__ cols,
        int* __restrict__ deg, int* __restrict__ ell,
        int E, int perBlock, int R, int GOCT, int GB,
        const float* __restrict__ x, const unsigned short* __restrict__ w1p,
        unsigned short* __restrict__ h1b, int N) {
    int bid = (int)blockIdx.x;
    int o = bid >> 3;
    int lane7 = bid & 7;
    int m = o / 3;
    int p = o - 3 * m;
    if (p == 2 && m < GOCT) {
        // ----- GEMM1 (MFMA): h1b[N,128] bf16 = bf16(x) @ w1p -----
        int gemmIdx = m * 8 + lane7;
        if (gemmIdx >= GB) return;
        int wave = threadIdx.x >> 6, lane = threadIdx.x & 63;
        int quad = lane >> 4, qr = lane & 15;
        int rowBase = gemmIdx * 64 + wave * 16;
        int arow = rowBase + qr;
        bool rowOK = arow < N;
        f32x4 acc[8] = {};
#pragma unroll
        for (int s = 0; s < 4; ++s) {
            bf16x8 a = {};
            if (rowOK) {
                const float* ap = x + (size_t)arow * DIN + s * 32 + quad * 8;
                float4 lo = *(const float4*)ap;
                float4 hi = *(const float4*)(ap + 4);
                a[0] = (short)f2bf(lo.x); a[1] = (short)f2bf(lo.y);
                a[2] = (short)f2bf(lo.z); a[3] = (short)f2bf(lo.w);
                a[4] = (short)f2bf(hi.x); a[5] = (short)f2bf(hi.y);
                a[6] = (short)f2bf(hi.z); a[7] = (short)f2bf(hi.w);
            }
#pragma unroll
            for (int t = 0; t < 8; ++t) {
                bf16x8 b = *(const bf16x8*)(w1p + ((size_t)(t * 4 + s) * 64 + lane) * 8);
                acc[t] = __builtin_amdgcn_mfma_f32_16x16x32_bf16(a, b, acc[t], 0, 0, 0);
            }
        }
#pragma unroll
        for (int t = 0; t < 8; ++t)
#pragma unroll
            for (int i = 0; i < 4; ++i) {
                int r = rowBase + quad * 4 + i;
                if (r < N) h1b[(size_t)r * DHID + t * 16 + qr] = f2bf(acc[t][i]);
            }
        return;
    }
    // ----- ELL fill, dst-range partitioned (group = bid&7 = XCD-affine), int4 scan -----
    int gemBefore = (m < GOCT) ? m : GOCT;
    int chunk = o - gemBefore;                  // 0 .. BPG-1
    int g = lane7;
    int lo = g * R, hi = lo + R;
    int eBeg = chunk * perBlock;
    int eEnd = eBeg + perBlock; if (eEnd > E) eEnd = E;
    for (int e = eBeg + 4 * threadIdx.x; e < eEnd; e += 4 * 256) {
        if (e + 3 < eEnd) {
            int4 c4 = *(const int4*)(cols + e);
            int4 r4 = *(const int4*)(rows + e);
            fill_edge(c4.x, r4.x, lo, hi, deg, ell);
            fill_edge(c4.y, r4.y, lo, hi, deg, ell);
            fill_edge(c4.z, r4.z, lo, hi, deg, ell);
            fill_edge(c4.w, r4.w, lo, hi, deg, ell);
        } else {
            for (int j = e; j < eEnd; ++j) fill_edge(cols[j], rows[j], lo, hi, deg, ell);
        }
    }
}

// ---------------- fused gather layer 1 + bias/self/relu + GEMM2 ----------------
// Block = 256 threads = 4 waves; block covers 64 dst nodes (wave v: 16 nodes,
// sequential). Gather phase (wide: half-wave per src row, 8B/lane) produces the
// 128-feat hact row in registers -> packed bf16 into LDS [64][136] (pad +8
// ushorts kills the 16-way ds_read_b128 bank conflict). One barrier. GEMM2
// phase: 4 waves x 16 rows MFMA (4 n-tiles x 4 k-steps) -> h2b global bf16.
__global__ __launch_bounds__(256) void k_gather1g2(const int* __restrict__ deg,
                                                   const int* __restrict__ ell,
                                                   const uint2* __restrict__ h1v,
                                                   const float* __restrict__ b1,
                                                   const unsigned short* __restrict__ w2p,
                                                   unsigned short* __restrict__ h2b, int N) {
    __shared__ unsigned short hact_s[64][136];
    int wv = threadIdx.x >> 6;
    int lane = threadIdx.x & 63;
    int half = lane >> 5, col = lane & 31;
    int base = blockIdx.x * 64;
    float4 bv = *(const float4*)(b1 + 4 * col);
    for (int i = 0; i < 16; ++i) {
        int w = base + wv * 16 + i;
        if (w >= N) break;                                      // wave-uniform
        int d = deg[w]; if (d > ELLW) d = ELLW;
        int iv0 = ell[(size_t)w * ELLW + lane];                 // 256B coalesced
        int iv = (lane < d) ? iv0 : 0;                          // safe index
        float dv = (lane < d) ? rsqrtf((float)(deg[iv] + 1)) : 0.f;
        float a0 = 0.f, a1 = 0.f, a2 = 0.f, a3 = 0.f;
        int e = 0;
        for (; e + 16 <= d; e += 16) {                          // 16 rows, 8 loads
            int s[8]; float wg[8]; uint2 v[8];
#pragma unroll
            for (int j = 0; j < 8; ++j) {
                int idx = e + 2 * j + half;
                s[j] = __shfl(iv, idx); wg[j] = __shfl(dv, idx);
            }
#pragma unroll
            for (int j = 0; j < 8; ++j) v[j] = h1v[(size_t)s[j] * 32 + col];
#pragma unroll
            for (int j = 0; j < 8; ++j) {
                a0 = fmaf(wg[j], bf2f(v[j].x & 0xffffu), a0);
                a1 = fmaf(wg[j], bf2f(v[j].x >> 16), a1);
                a2 = fmaf(wg[j], bf2f(v[j].y & 0xffffu), a2);
                a3 = fmaf(wg[j], bf2f(v[j].y >> 16), a3);
            }
        }
        for (; e + 8 <= d; e += 8) {                            // 8 rows, 4 loads
            int s[4]; float wg[4]; uint2 v[4];
#pragma unroll
            for (int j = 0; j < 4; ++j) {
                int idx = e + 2 * j + half;
                s[j] = __shfl(iv, idx); wg[j] = __shfl(dv, idx);
            }
#pragma unroll
            for (int j = 0; j < 4; ++j) v[j] = h1v[(size_t)s[j] * 32 + col];
#pragma unroll
            for (int j = 0; j < 4; ++j) {
                a0 = fmaf(wg[j], bf2f(v[j].x & 0xffffu), a0);
                a1 = fmaf(wg[j], bf2f(v[j].x >> 16), a1);
                a2 = fmaf(wg[j], bf2f(v[j].y & 0xffffu), a2);
                a3 = fmaf(wg[j], bf2f(v[j].y >> 16), a3);
            }
        }
        for (; e < d; e += 2) {                                 // tail pair
            int idx = e + half;                                 // beyond-d lanes: wg=0
            int s0 = __shfl(iv, idx); float w0 = __shfl(dv, idx);
            uint2 v0 = h1v[(size_t)s0 * 32 + col];
            a0 = fmaf(w0, bf2f(v0.x & 0xffffu), a0);
            a1 = fmaf(w0, bf2f(v0.x >> 16), a1);
            a2 = fmaf(w0, bf2f(v0.y & 0xffffu), a2);
            a3 = fmaf(w0, bf2f(v0.y >> 16), a3);
        }
        a0 += __shfl_xor(a0, 32); a1 += __shfl_xor(a1, 32);
        a2 += __shfl_xor(a2, 32); a3 += __shfl_xor(a3, 32);
        float di = rsqrtf((float)(d + 1)), self = di * di;
        uint2 hv = h1v[(size_t)w * 32 + col];
        float r0 = fmaf(di, a0, fmaf(self, bf2f(hv.x & 0xffffu), bv.x));
        float r1 = fmaf(di, a1, fmaf(self, bf2f(hv.x >> 16), bv.y));
        float r2 = fmaf(di, a2, fmaf(self, bf2f(hv.y & 0xffffu), bv.z));
        float r3 = fmaf(di, a3, fmaf(self, bf2f(hv.y >> 16), bv.w));
        if (lane < 32) {
            uint2 ov;
            ov.x = pack2(fmaxf(r0, 0.f), fmaxf(r1, 0.f));
            ov.y = pack2(fmaxf(r2, 0.f), fmaxf(r3, 0.f));
            *(uint2*)&hact_s[wv * 16 + i][4 * col] = ov;
        }
    }
    __syncthreads();
    // ----- GEMM2 phase: h2[base+wv*16 .. +16][64] = hact_s rows @ w2p -----
    int quad = lane >> 4, qr = lane & 15;
    int arow = wv * 16 + qr;                                    // LDS A-row
    f32x4 acc[4] = {};
#pragma unroll
    for (int s = 0; s < 4; ++s) {
        bf16x8 a = *(const bf16x8*)&hact_s[arow][s * 32 + quad * 8];
#pragma unroll
        for (int t = 0; t < 4; ++t) {
            bf16x8 b = *(const bf16x8*)(w2p + ((size_t)(t * 4 + s) * 64 + lane) * 8);
            acc[t] = __builtin_amdgcn_mfma_f32_16x16x32_bf16(a, b, acc[t], 0, 0, 0);
        }
    }
#pragma unroll
    for (int t = 0; t < 4; ++t)
#pragma unroll
        for (int i = 0; i < 4; ++i) {
            int r = base + wv * 16 + quad * 4 + i;
            if (r < N) h2b[(size_t)r * DOUT + t * 16 + qr] = f2bf(acc[t][i]);
        }
}

// ---------------- gather layer 2 (wide): 2 rows/round, 4B/lane; writes f32 out ----------------
__global__ __launch_bounds__(256) void k_gather2(const int* __restrict__ deg,
                                                 const int* __restrict__ ell,
                                                 const unsigned int* __restrict__ h2v,
                                                 const float* __restrict__ b2,
                                                 float* __restrict__ out, int N) {
    int w = (blockIdx.x * 256 + threadIdx.x) >> 6;
    int lane = threadIdx.x & 63;
    if (w >= N) return;
    int d = deg[w]; if (d > ELLW) d = ELLW;
    int iv0 = ell[(size_t)w * ELLW + lane];
    int iv = (lane < d) ? iv0 : 0;
    float dv = (lane < d) ? rsqrtf((float)(deg[iv] + 1)) : 0.f;
    int half = lane >> 5, col = lane & 31;
    float a0 = 0.f, a1 = 0.f;
    int e = 0;
    for (; e + 16 <= d; e += 16) {
        int s[8]; float wg[8]; unsigned int v[8];
#pragma unroll
        for (int j = 0; j < 8; ++j) {
            int idx = e + 2 * j + half;
            s[j] = __shfl(iv, idx); wg[j] = __shfl(dv, idx);
        }
#pragma unroll
        for (int j = 0; j < 8; ++j) v[j] = h2v[(size_t)s[j] * 32 + col];
#pragma unroll
        for (int j = 0; j < 8; ++j) {
            a0 = fmaf(wg[j], bf2f(v[j] & 0xffffu), a0);
            a1 = fmaf(wg[j], bf2f(v[j] >> 16), a1);
        }
    }
    for (; e + 8 <= d; e += 8) {
        int s[4]; float wg[4]; unsigned int v[4];
#pragma unroll
        for (int j = 0; j < 4; ++j) {
            int idx = e + 2 * j + half;
            s[j] = __shfl(iv, idx); wg[j] = __shfl(dv, idx);
        }
#pragma unroll
        for (int j = 0; j < 4; ++j) v[j] = h2v[(size_t)s[j] * 32 + col];
#pragma unroll
        for (int j = 0; j < 4; ++j) {
            a0 = fmaf(wg[j], bf2f(v[j] & 0xffffu), a0);
            a1 = fmaf(wg[j], bf2f(v[j] >> 16), a1);
        }
    }
    for (; e < d; e += 2) {
        int idx = e + half;
        int s0 = __shfl(iv, idx); float w0 = __shfl(dv, idx);
        unsigned int v0 = h2v[(size_t)s0 * 32 + col];
        a0 = fmaf(w0, bf2f(v0 & 0xffffu), a0);
        a1 = fmaf(w0, bf2f(v0 >> 16), a1);
    }
    a0 += __shfl_xor(a0, 32); a1 += __shfl_xor(a1, 32);
    float di = rsqrtf((float)(d + 1)), self = di * di;
    unsigned int hv = h2v[(size_t)w * 32 + col];
    float2 bv = *(const float2*)(b2 + 2 * col);
    float r0 = fmaf(di, a0, fmaf(self, bf2f(hv & 0xffffu), bv.x));
    float r1 = fmaf(di, a1, fmaf(self, bf2f(hv >> 16), bv.y));
    if (lane < 32) {
        float2 ov; ov.x = r0; ov.y = r1;
        *(float2*)(out + (size_t)w * DOUT + 2 * col) = ov;
    }
}

extern "C" void kernel_launch(void* const* d_in, const int* in_sizes, int n_in,
                              void* d_out, int out_size, void* d_ws, size_t ws_size,
                              hipStream_t stream) {
    const float* x  = (const float*)d_in[0];
    const int*   ei = (const int*)d_in[1];
    const float* W1 = (const float*)d_in[2];
    const float* b1 = (const float*)d_in[3];
    const float* W2 = (const float*)d_in[4];
    const float* b2 = (const float*)d_in[5];

    const int N = in_sizes[0] / DIN;     // 100000
    const int E = in_sizes[1] / 2;       // 1600000
    const int* rows = ei;                // sources
    const int* cols = ei + E;            // destinations

    // workspace (~64.5 MB)
    char* p = (char*)d_ws;
    int*   ell  = (int*)p;                    p += (size_t)N * ELLW * 4;   // 25.6 MB
    unsigned short* h1b = (unsigned short*)p;   p += (size_t)N * DHID * 2; // 25.6 MB
    unsigned short* h2b = (unsigned short*)p;   p += (size_t)N * DOUT * 2; // 12.8 MB
    unsigned short* w1p = (unsigned short*)p;   p += (size_t)2048 * 8 * 2; // 32 KB
    unsigned short* w2p = (unsigned short*)p;   p += (size_t)1024 * 8 * 2; // 16 KB
    int*   deg  = (int*)p;                    p += (size_t)N * 4;          // 0.4 MB

    const int R = (N + GPART - 1) / GPART;
    int perBlock = (E + BPG - 1) / BPG;
    perBlock = (perBlock + 3) & ~3;                  // int4-aligned chunks
    const int GB = (N + 63) / 64;                    // 1563 gemm tiles
    const int GOCT = (GB + 7) / 8;                   // 196 gemm octets
    const int OCT = BPG + GOCT;                      // 708 octets total

    k_packW<<<12, 256, 0, stream>>>(W1, W2, w1p, w2p, deg, N);

    // fill + gemm1, octet-interleaved (concurrent on every CU)
    k_fill_gemm1<<<8 * OCT, 256, 0, stream>>>(rows, cols, deg, ell, E, perBlock, R,
                                              GOCT, GB, x, w1p, h1b, N);

    // layer 1 aggregate + fused GEMM2 (LDS tile, one barrier)
    k_gather1g2<<<(N + 63) / 64, 256, 0, stream>>>(deg, ell, (const uint2*)h1b,
                                                   b1, w2p, h2b, N);

    // layer 2 aggregate
    k_gather2<<<(N + 3) / 4, 256, 0, stream>>>(deg, ell, (const unsigned int*)h2b,
                                               b2, (float*)d_out, N);
}

// Round 8
// 294.842 us; speedup vs baseline: 1.1664x; 1.0941x over previous
//
#include <hip/hip_runtime.h>

// GCN 2-layer forward. f32 wire; bf16 MFMA GEMMs (f32 acc); bf16 gather tables;
// padded-ELL adjacency; octet-interleaved fill+gemm1 (XCD-affine atomics).
// This round: fix R7's fused-kernel occupancy (16-node blocks, grid 6250 — R7's
// 64-node blocks gave 6.1 blocks/CU, 33% occupancy, throttled gather TLP);
// parallel masked tail round in both gathers (old dependent 2-row tail = up to
// 3-4 serial load round-trips/node); ELL row read masked to lane<d.

#define DIN 128
#define DHID 128
#define DOUT 64
#define ELLW 64     // max in-degree (Poisson(16): P(>=64) ~ 1e-22)
#define GPART 8
#define BPG 512

typedef __attribute__((ext_vector_type(4))) float f32x4;
typedef __attribute__((ext_vector_type(8))) short bf16x8;

__device__ __forceinline__ float bf2f(unsigned int u16) {
    return __uint_as_float(u16 << 16);
}
__device__ __forceinline__ unsigned short f2bf(float f) {
    unsigned int u = __float_as_uint(f);
    u += 0x7fffu + ((u >> 16) & 1u);   // RNE
    return (unsigned short)(u >> 16);
}
__device__ __forceinline__ unsigned int pack2(float a, float b) {
    return (unsigned int)f2bf(a) | ((unsigned int)f2bf(b) << 16);
}

// ---------------- pack W1/W2 into MFMA B-fragment order, bf16; zero deg ----------------
__global__ __launch_bounds__(256) void k_packW(const float* __restrict__ W1,
                                               const float* __restrict__ W2,
                                               unsigned short* __restrict__ w1p,
                                               unsigned short* __restrict__ w2p,
                                               int* __restrict__ deg, int N) {
    int id = blockIdx.x * 256 + threadIdx.x;
    if (id < 2048) {                     // W1: 8 n-tiles x 4 k-steps x 64 lanes
        int lane = id & 63, s = (id >> 6) & 3, t = id >> 8;
        int n = t * 16 + (lane & 15);
        int k0 = s * 32 + (lane >> 4) * 8;
#pragma unroll
        for (int j = 0; j < 8; ++j)
            w1p[(size_t)id * 8 + j] = f2bf(W1[(k0 + j) * DHID + n]);
    } else if (id < 3072) {              // W2: 4 n-tiles x 4 k-steps x 64 lanes
        int id2 = id - 2048;
        int lane = id2 & 63, s = (id2 >> 6) & 3, t = id2 >> 8;
        int n = t * 16 + (lane & 15);
        int k0 = s * 32 + (lane >> 4) * 8;
#pragma unroll
        for (int j = 0; j < 8; ++j)
            w2p[(size_t)id2 * 8 + j] = f2bf(W2[(k0 + j) * DOUT + n]);
    }
    for (int i = id; i < N; i += 12 * 256) deg[i] = 0;
}

// ---------------- fused: ELL fill + GEMM1, octet-interleaved roles ----------------
__device__ __forceinline__ void fill_edge(int c, int r, int lo, int hi,
                                          int* __restrict__ deg, int* __restrict__ ell) {
    if (c >= lo && c < hi) {
        int k = atomicAdd(&deg[c], 1);
        if (k < ELLW) ell[(size_t)c * ELLW + k] = r;
    }
}

__global__ __launch_bounds__(256) void k_fill_gemm1(
        const int* __restrict__ rows, const int* __restrict__ cols,
        int* __restrict__ deg, int* __restrict__ ell,
        int E, int perBlock, int R, int GOCT, int GB,
        const float* __restrict__ x, const unsigned short* __restrict__ w1p,
        unsigned short* __restrict__ h1b, int N) {
    int bid = (int)blockIdx.x;
    int o = bid >> 3;
    int lane7 = bid & 7;
    int m = o / 3;
    int p = o - 3 * m;
    if (p == 2 && m < GOCT) {
        // ----- GEMM1 (MFMA): h1b[N,128] bf16 = bf16(x) @ w1p -----
        int gemmIdx = m * 8 + lane7;
        if (gemmIdx >= GB) return;
        int wave = threadIdx.x >> 6, lane = threadIdx.x & 63;
        int quad = lane >> 4, qr = lane & 15;
        int rowBase = gemmIdx * 64 + wave * 16;
        int arow = rowBase + qr;
        bool rowOK = arow < N;
        f32x4 acc[8] = {};
#pragma unroll
        for (int s = 0; s < 4; ++s) {
            bf16x8 a = {};
            if (rowOK) {
                const float* ap = x + (size_t)arow * DIN + s * 32 + quad * 8;
                float4 lo = *(const float4*)ap;
                float4 hi = *(const float4*)(ap + 4);
                a[0] = (short)f2bf(lo.x); a[1] = (short)f2bf(lo.y);
                a[2] = (short)f2bf(lo.z); a[3] = (short)f2bf(lo.w);
                a[4] = (short)f2bf(hi.x); a[5] = (short)f2bf(hi.y);
                a[6] = (short)f2bf(hi.z); a[7] = (short)f2bf(hi.w);
            }
#pragma unroll
            for (int t = 0; t < 8; ++t) {
                bf16x8 b = *(const bf16x8*)(w1p + ((size_t)(t * 4 + s) * 64 + lane) * 8);
                acc[t] = __builtin_amdgcn_mfma_f32_16x16x32_bf16(a, b, acc[t], 0, 0, 0);
            }
        }
#pragma unroll
        for (int t = 0; t < 8; ++t)
#pragma unroll
            for (int i = 0; i < 4; ++i) {
                int r = rowBase + quad * 4 + i;
                if (r < N) h1b[(size_t)r * DHID + t * 16 + qr] = f2bf(acc[t][i]);
            }
        return;
    }
    // ----- ELL fill, dst-range partitioned (group = bid&7 = XCD-affine), int4 scan -----
    int gemBefore = (m < GOCT) ? m : GOCT;
    int chunk = o - gemBefore;                  // 0 .. BPG-1
    int g = lane7;
    int lo = g * R, hi = lo + R;
    int eBeg = chunk * perBlock;
    int eEnd = eBeg + perBlock; if (eEnd > E) eEnd = E;
    for (int e = eBeg + 4 * threadIdx.x; e < eEnd; e += 4 * 256) {
        if (e + 3 < eEnd) {
            int4 c4 = *(const int4*)(cols + e);
            int4 r4 = *(const int4*)(rows + e);
            fill_edge(c4.x, r4.x, lo, hi, deg, ell);
            fill_edge(c4.y, r4.y, lo, hi, deg, ell);
            fill_edge(c4.z, r4.z, lo, hi, deg, ell);
            fill_edge(c4.w, r4.w, lo, hi, deg, ell);
        } else {
            for (int j = e; j < eEnd; ++j) fill_edge(cols[j], rows[j], lo, hi, deg, ell);
        }
    }
}

// ---------------- fused gather layer 1 + bias/self/relu + GEMM2 ----------------
// Block = 256 threads = 4 waves; block covers 16 dst nodes (wave v: nodes
// 4v..4v+3, sequential). Gather (wide: half-wave per src row, 8B/lane) -> bf16
// into LDS [16][136]. One barrier. GEMM2: every wave reads all 16 rows, wave v
// computes n-tile v (4 k-step MFMAs) -> h2b[*, 16v..16v+15]. Grid 6250 blocks
// keeps occupancy at the wave-slot limit (R7's 64-node blocks = 33% occ).
__global__ __launch_bounds__(256) void k_gather1g2(const int* __restrict__ deg,
                                                   const int* __restrict__ ell,
                                                   const uint2* __restrict__ h1v,
                                                   const float* __restrict__ b1,
                                                   const unsigned short* __restrict__ w2p,
                                                   unsigned short* __restrict__ h2b, int N) {
    __shared__ unsigned short hact_s[16][136];
    int wv = threadIdx.x >> 6;
    int lane = threadIdx.x & 63;
    int half = lane >> 5, col = lane & 31;
    int base = blockIdx.x * 16;
    float4 bv = *(const float4*)(b1 + 4 * col);
    for (int i = 0; i < 4; ++i) {
        int w = base + wv * 4 + i;
        if (w < N) {
            int d = deg[w]; if (d > ELLW) d = ELLW;
            int iv = 0;
            if (lane < d) iv = ell[(size_t)w * ELLW + lane];    // masked: ~2 lines/node
            float dv = (lane < d) ? rsqrtf((float)(deg[iv] + 1)) : 0.f;
            float a0 = 0.f, a1 = 0.f, a2 = 0.f, a3 = 0.f;
            int e = 0;
            for (; e + 16 <= d; e += 16) {                      // 16 rows, 8 loads
                int s[8]; float wg[8]; uint2 v[8];
#pragma unroll
                for (int j = 0; j < 8; ++j) {
                    int idx = e + 2 * j + half;
                    s[j] = __shfl(iv, idx); wg[j] = __shfl(dv, idx);
                }
#pragma unroll
                for (int j = 0; j < 8; ++j) v[j] = h1v[(size_t)s[j] * 32 + col];
#pragma unroll
                for (int j = 0; j < 8; ++j) {
                    a0 = fmaf(wg[j], bf2f(v[j].x & 0xffffu), a0);
                    a1 = fmaf(wg[j], bf2f(v[j].x >> 16), a1);
                    a2 = fmaf(wg[j], bf2f(v[j].y & 0xffffu), a2);
                    a3 = fmaf(wg[j], bf2f(v[j].y >> 16), a3);
                }
            }
            if (e + 8 <= d) {                                   // 8 rows, 4 loads
                int s[4]; float wg[4]; uint2 v[4];
#pragma unroll
                for (int j = 0; j < 4; ++j) {
                    int idx = e + 2 * j + half;
                    s[j] = __shfl(iv, idx); wg[j] = __shfl(dv, idx);
                }
#pragma unroll
                for (int j = 0; j < 4; ++j) v[j] = h1v[(size_t)s[j] * 32 + col];
#pragma unroll
                for (int j = 0; j < 4; ++j) {
                    a0 = fmaf(wg[j], bf2f(v[j].x & 0xffffu), a0);
                    a1 = fmaf(wg[j], bf2f(v[j].x >> 16), a1);
                    a2 = fmaf(wg[j], bf2f(v[j].y & 0xffffu), a2);
                    a3 = fmaf(wg[j], bf2f(v[j].y >> 16), a3);
                }
                e += 8;
            }
            if (e < d) {                                        // masked parallel tail
                int s[4]; float wg[4]; uint2 v[4];
#pragma unroll
                for (int j = 0; j < 4; ++j) {
                    int idx = e + 2 * j + half;
                    int cl = idx < 63 ? idx : 63;
                    s[j] = __shfl(iv, cl);
                    float t = __shfl(dv, cl);
                    wg[j] = (idx < d) ? t : 0.f;
                }
#pragma unroll
                for (int j = 0; j < 4; ++j) v[j] = h1v[(size_t)s[j] * 32 + col];
#pragma unroll
                for (int j = 0; j < 4; ++j) {
                    a0 = fmaf(wg[j], bf2f(v[j].x & 0xffffu), a0);
                    a1 = fmaf(wg[j], bf2f(v[j].x >> 16), a1);
                    a2 = fmaf(wg[j], bf2f(v[j].y & 0xffffu), a2);
                    a3 = fmaf(wg[j], bf2f(v[j].y >> 16), a3);
                }
            }
            a0 += __shfl_xor(a0, 32); a1 += __shfl_xor(a1, 32);
            a2 += __shfl_xor(a2, 32); a3 += __shfl_xor(a3, 32);
            float di = rsqrtf((float)(d + 1)), self = di * di;
            uint2 hv = h1v[(size_t)w * 32 + col];
            float r0 = fmaf(di, a0, fmaf(self, bf2f(hv.x & 0xffffu), bv.x));
            float r1 = fmaf(di, a1, fmaf(self, bf2f(hv.x >> 16), bv.y));
            float r2 = fmaf(di, a2, fmaf(self, bf2f(hv.y & 0xffffu), bv.z));
            float r3 = fmaf(di, a3, fmaf(self, bf2f(hv.y >> 16), bv.w));
            if (lane < 32) {
                uint2 ov;
                ov.x = pack2(fmaxf(r0, 0.f), fmaxf(r1, 0.f));
                ov.y = pack2(fmaxf(r2, 0.f), fmaxf(r3, 0.f));
                *(uint2*)&hact_s[wv * 4 + i][4 * col] = ov;
            }
        } else if (lane < 32) {
            uint2 z; z.x = 0u; z.y = 0u;
            *(uint2*)&hact_s[wv * 4 + i][4 * col] = z;
        }
    }
    __syncthreads();
    // ----- GEMM2 phase: wave wv computes n-tile wv of rows base..base+15 -----
    int quad = lane >> 4, qr = lane & 15;
    f32x4 acc = {};
#pragma unroll
    for (int s = 0; s < 4; ++s) {
        bf16x8 a = *(const bf16x8*)&hact_s[qr][s * 32 + quad * 8];
        bf16x8 b = *(const bf16x8*)(w2p + ((size_t)(wv * 4 + s) * 64 + lane) * 8);
        acc = __builtin_amdgcn_mfma_f32_16x16x32_bf16(a, b, acc, 0, 0, 0);
    }
#pragma unroll
    for (int i = 0; i < 4; ++i) {
        int r = base + quad * 4 + i;
        if (r < N) h2b[(size_t)r * DOUT + wv * 16 + qr] = f2bf(acc[i]);
    }
}

// ---------------- gather layer 2 (wide): 2 rows/round, 4B/lane; writes f32 out ----------------
__global__ __launch_bounds__(256) void k_gather2(const int* __restrict__ deg,
                                                 const int* __restrict__ ell,
                                                 const unsigned int* __restrict__ h2v,
                                                 const float* __restrict__ b2,
                                                 float* __restrict__ out, int N) {
    int w = (blockIdx.x * 256 + threadIdx.x) >> 6;
    int lane = threadIdx.x & 63;
    if (w >= N) return;
    int d = deg[w]; if (d > ELLW) d = ELLW;
    int iv = 0;
    if (lane < d) iv = ell[(size_t)w * ELLW + lane];            // masked read
    float dv = (lane < d) ? rsqrtf((float)(deg[iv] + 1)) : 0.f;
    int half = lane >> 5, col = lane & 31;
    float a0 = 0.f, a1 = 0.f;
    int e = 0;
    for (; e + 16 <= d; e += 16) {
        int s[8]; float wg[8]; unsigned int v[8];
#pragma unroll
        for (int j = 0; j < 8; ++j) {
            int idx = e + 2 * j + half;
            s[j] = __shfl(iv, idx); wg[j] = __shfl(dv, idx);
        }
#pragma unroll
        for (int j = 0; j < 8; ++j) v[j] = h2v[(size_t)s[j] * 32 + col];
#pragma unroll
        for (int j = 0; j < 8; ++j) {
            a0 = fmaf(wg[j], bf2f(v[j] & 0xffffu), a0);
            a1 = fmaf(wg[j], bf2f(v[j] >> 16), a1);
        }
    }
    if (e + 8 <= d) {
        int s[4]; float wg[4]; unsigned int v[4];
#pragma unroll
        for (int j = 0; j < 4; ++j) {
            int idx = e + 2 * j + half;
            s[j] = __shfl(iv, idx); wg[j] = __shfl(dv, idx);
        }
#pragma unroll
        for (int j = 0; j < 4; ++j) v[j] = h2v[(size_t)s[j] * 32 + col];
#pragma unroll
        for (int j = 0; j < 4; ++j) {
            a0 = fmaf(wg[j], bf2f(v[j] & 0xffffu), a0);
            a1 = fmaf(wg[j], bf2f(v[j] >> 16), a1);
        }
        e += 8;
    }
    if (e < d) {                                                // masked parallel tail
        int s[4]; float wg[4]; unsigned int v[4];
#pragma unroll
        for (int j = 0; j < 4; ++j) {
            int idx = e + 2 * j + half;
            int cl = idx < 63 ? idx : 63;
            s[j] = __shfl(iv, cl);
            float t = __shfl(dv, cl);
            wg[j] = (idx < d) ? t : 0.f;
        }
#pragma unroll
        for (int j = 0; j < 4; ++j) v[j] = h2v[(size_t)s[j] * 32 + col];
#pragma unroll
        for (int j = 0; j < 4; ++j) {
            a0 = fmaf(wg[j], bf2f(v[j] & 0xffffu), a0);
            a1 = fmaf(wg[j], bf2f(v[j] >> 16), a1);
        }
    }
    a0 += __shfl_xor(a0, 32); a1 += __shfl_xor(a1, 32);
    float di = rsqrtf((float)(d + 1)), self = di * di;
    unsigned int hv = h2v[(size_t)w * 32 + col];
    float2 bv = *(const float2*)(b2 + 2 * col);
    float r0 = fmaf(di, a0, fmaf(self, bf2f(hv & 0xffffu), bv.x));
    float r1 = fmaf(di, a1, fmaf(self, bf2f(hv >> 16), bv.y));
    if (lane < 32) {
        float2 ov; ov.x = r0; ov.y = r1;
        *(float2*)(out + (size_t)w * DOUT + 2 * col) = ov;
    }
}

extern "C" void kernel_launch(void* const* d_in, const int* in_sizes, int n_in,
                              void* d_out, int out_size, void* d_ws, size_t ws_size,
                              hipStream_t stream) {
    const float* x  = (const float*)d_in[0];
    const int*   ei = (const int*)d_in[1];
    const float* W1 = (const float*)d_in[2];
    const float* b1 = (const float*)d_in[3];
    const float* W2 = (const float*)d_in[4];
    const float* b2 = (const float*)d_in[5];

    const int N = in_sizes[0] / DIN;     // 100000
    const int E = in_sizes[1] / 2;       // 1600000
    const int* rows = ei;                // sources
    const int* cols = ei + E;            // destinations

    // workspace (~64.5 MB)
    char* p = (char*)d_ws;
    int*   ell  = (int*)p;                    p += (size_t)N * ELLW * 4;   // 25.6 MB
    unsigned short* h1b = (unsigned short*)p;   p += (size_t)N * DHID * 2; // 25.6 MB
    unsigned short* h2b = (unsigned short*)p;   p += (size_t)N * DOUT * 2; // 12.8 MB
    unsigned short* w1p = (unsigned short*)p;   p += (size_t)2048 * 8 * 2; // 32 KB
    unsigned short* w2p = (unsigned short*)p;   p += (size_t)1024 * 8 * 2; // 16 KB
    int*   deg  = (int*)p;                    p += (size_t)N * 4;          // 0.4 MB

    const int R = (N + GPART - 1) / GPART;
    int perBlock = (E + BPG - 1) / BPG;
    perBlock = (perBlock + 3) & ~3;                  // int4-aligned chunks
    const int GB = (N + 63) / 64;                    // 1563 gemm tiles
    const int GOCT = (GB + 7) / 8;                   // 196 gemm octets
    const int OCT = BPG + GOCT;                      // 708 octets total

    k_packW<<<12, 256, 0, stream>>>(W1, W2, w1p, w2p, deg, N);

    // fill + gemm1, octet-interleaved (concurrent on every CU)
    k_fill_gemm1<<<8 * OCT, 256, 0, stream>>>(rows, cols, deg, ell, E, perBlock, R,
                                              GOCT, GB, x, w1p, h1b, N);

    // layer 1 aggregate + fused GEMM2 (16-node blocks, high occupancy)
    k_gather1g2<<<(N + 15) / 16, 256, 0, stream>>>(deg, ell, (const uint2*)h1b,
                                                   b1, w2p, h2b, N);

    // layer 2 aggregate
    k_gather2<<<(N + 3) / 4, 256, 0, stream>>>(deg, ell, (const unsigned int*)h2b,
                                               b2, (float*)d_out, N);
}